// Round 1
// baseline (337.137 us; speedup 1.0000x reference)
//
#include <hip/hip_runtime.h>
#include <cstddef>

#define NB 256     // graphs
#define M 512      // nodes per graph
#define KNN 6      // neighbors
#define C 32       // channels
#define NTOT (NB*M)

// ---------------------------------------------------------------------------
// KNN: one block per graph, one thread per row. Positions + sq norms in LDS.
// Replicates reference d2 = sq[m] + sq[n] - 2*dot, stable (lowest-index) ties.
// ---------------------------------------------------------------------------
__global__ __launch_bounds__(512) void knn_kernel(const float* __restrict__ pos,
                                                  int* __restrict__ idx)
{
    __shared__ float sx[M], sy[M], sz[M], ssq[M];
    const int g = blockIdx.x;
    const float* p = pos + (size_t)g * M * 3;
    for (int i = threadIdx.x; i < M; i += blockDim.x) {
        float x = p[i * 3 + 0], y = p[i * 3 + 1], z = p[i * 3 + 2];
        sx[i] = x; sy[i] = y; sz[i] = z;
        ssq[i] = fmaf(x, x, fmaf(y, y, z * z));
    }
    __syncthreads();

    const int m = threadIdx.x;
    const float xm = sx[m], ym = sy[m], zm = sz[m], sqm = ssq[m];

    float d[KNN];
    int   id[KNN];
#pragma unroll
    for (int k = 0; k < KNN; k++) { d[k] = INFINITY; id[k] = -1; }

    for (int n = 0; n < M; n++) {
        float dot  = fmaf(xm, sx[n], fmaf(ym, sy[n], zm * sz[n]));
        float dist = fmaf(-2.f, dot, sqm + ssq[n]);   // == (sqm+sqn) - 2*dot, 1 rounding
        if (dist < d[KNN - 1]) {                      // wave-skips when no lane inserts
            // branchless sorted insert; strict < keeps earlier index on ties
#pragma unroll
            for (int k = KNN - 1; k > 0; k--) {
                bool ck   = dist < d[k];
                bool ckm1 = dist < d[k - 1];
                d[k]  = ckm1 ? d[k - 1]  : (ck ? dist : d[k]);
                id[k] = ckm1 ? id[k - 1] : (ck ? n    : id[k]);
            }
            if (dist < d[0]) { d[0] = dist; id[0] = n; }
        }
    }

    int* o = idx + ((size_t)g * M + m) * KNN;
#pragma unroll
    for (int k = 0; k < KNN; k++) o[k] = id[k];
}

// ---------------------------------------------------------------------------
// Per-node MLP: t[n] = W2 @ relu(W1 @ h[n] + b1) + b2.
// Messages depend only on the source node => compute once per node (6x fewer
// MLPs than per-edge). Weights are wave-uniform -> scalar loads from global.
// ---------------------------------------------------------------------------
template <int IN>
__global__ __launch_bounds__(256) void transform_kernel(
    const float* __restrict__ Hin,   // N x IN (node-major), used when IN==C
    const float* __restrict__ xin,   // N x 1  (layer A)
    const float* __restrict__ posin, // N x 3  (layer A)
    const float* __restrict__ W1, const float* __restrict__ b1,
    const float* __restrict__ W2, const float* __restrict__ b2,
    float* __restrict__ T)
{
    const int n = blockIdx.x * blockDim.x + threadIdx.x;

    float h[IN];
    if constexpr (IN == 4) {
        h[0] = xin[n];
        h[1] = posin[n * 3 + 0];
        h[2] = posin[n * 3 + 1];
        h[3] = posin[n * 3 + 2];
    } else {
#pragma unroll
        for (int i = 0; i < IN; i++) h[i] = Hin[(size_t)n * IN + i];
    }

    float m1[C];
#pragma unroll
    for (int o = 0; o < C; o++) {
        float acc = b1[o];
#pragma unroll
        for (int i = 0; i < IN; i++) acc = fmaf(W1[o * IN + i], h[i], acc);
        m1[o] = fmaxf(acc, 0.f);
    }

#pragma unroll
    for (int o = 0; o < C; o++) {
        float acc = b2[o];
#pragma unroll
        for (int i = 0; i < C; i++) acc = fmaf(W2[o * C + i], m1[i], acc);
        T[(size_t)n * C + o] = acc;
    }
}

// ---------------------------------------------------------------------------
// Aggregate: h'[n][c] = relu(max_k t[nbr(n,k)][c]). Thread per (node,channel).
// ---------------------------------------------------------------------------
__global__ __launch_bounds__(256) void aggregate_kernel(
    const float* __restrict__ T, const int* __restrict__ idx,
    float* __restrict__ Hout)
{
    const int gid = blockIdx.x * blockDim.x + threadIdx.x; // NTOT*C threads
    const int n = gid / C;
    const int c = gid % C;
    const int* row = idx + (size_t)n * KNN;
    const size_t base = (size_t)(n / M) * M;   // graph's first node

    float acc = -INFINITY;
#pragma unroll
    for (int k = 0; k < KNN; k++) {
        int j = row[k];
        acc = fmaxf(acc, T[(base + (size_t)j) * C + c]);
    }
    Hout[(size_t)n * C + c] = fmaxf(acc, 0.f);
}

// ---------------------------------------------------------------------------
// Global max pool per graph + final linear head. One block per graph.
// ---------------------------------------------------------------------------
__global__ __launch_bounds__(256) void pool_head_kernel(
    const float* __restrict__ H, const float* __restrict__ Wr,
    const float* __restrict__ br, float* __restrict__ out)
{
    __shared__ float red[8][C];
    const int g = blockIdx.x;
    const int c = threadIdx.x % C;
    const int chunk = threadIdx.x / C;   // 0..7, 64 nodes each

    float acc = 0.f;   // H >= 0 after relu
    const float* base = H + ((size_t)g * M + (size_t)chunk * 64) * C;
    for (int i = 0; i < 64; i++)
        acc = fmaxf(acc, base[i * C + c]);
    red[chunk][c] = acc;
    __syncthreads();

    if (threadIdx.x < C) {
        float mx = red[0][threadIdx.x];
#pragma unroll
        for (int k = 1; k < 8; k++) mx = fmaxf(mx, red[k][threadIdx.x]);
        red[0][threadIdx.x] = mx;
    }
    __syncthreads();

    if (threadIdx.x < 6) {
        float acc2 = br[threadIdx.x];
#pragma unroll
        for (int i = 0; i < C; i++)
            acc2 = fmaf(Wr[threadIdx.x * C + i], red[0][i], acc2);
        out[(size_t)g * 6 + threadIdx.x] = acc2;
    }
}

extern "C" void kernel_launch(void* const* d_in, const int* in_sizes, int n_in,
                              void* d_out, int out_size, void* d_ws, size_t ws_size,
                              hipStream_t stream) {
    const float* x   = (const float*)d_in[0];
    const float* pos = (const float*)d_in[1];
    // d_in[2] = batch (int64) unused: nodes are contiguous M-per-graph
    const float* W1a = (const float*)d_in[3];
    const float* b1a = (const float*)d_in[4];
    const float* W2a = (const float*)d_in[5];
    const float* b2a = (const float*)d_in[6];
    const float* W1b = (const float*)d_in[7];
    const float* b1b = (const float*)d_in[8];
    const float* W2b = (const float*)d_in[9];
    const float* b2b = (const float*)d_in[10];
    const float* W1c = (const float*)d_in[11];
    const float* b1c = (const float*)d_in[12];
    const float* W2c = (const float*)d_in[13];
    const float* b2c = (const float*)d_in[14];
    const float* Wr  = (const float*)d_in[15];
    const float* br  = (const float*)d_in[16];

    char* ws = (char*)d_ws;
    int*   idx  = (int*)ws;                                   // 3.0 MB
    float* bufT = (float*)(ws + (size_t)4 * 1024 * 1024);     // 16.8 MB
    float* bufH = (float*)(ws + (size_t)24 * 1024 * 1024);    // 16.8 MB

    float* out = (float*)d_out;

    knn_kernel<<<NB, 512, 0, stream>>>(pos, idx);

    transform_kernel<4><<<NTOT / 256, 256, 0, stream>>>(
        nullptr, x, pos, W1a, b1a, W2a, b2a, bufT);
    aggregate_kernel<<<(NTOT * C) / 256, 256, 0, stream>>>(bufT, idx, bufH);

    transform_kernel<C><<<NTOT / 256, 256, 0, stream>>>(
        bufH, nullptr, nullptr, W1b, b1b, W2b, b2b, bufT);
    aggregate_kernel<<<(NTOT * C) / 256, 256, 0, stream>>>(bufT, idx, bufH);

    transform_kernel<C><<<NTOT / 256, 256, 0, stream>>>(
        bufH, nullptr, nullptr, W1c, b1c, W2c, b2c, bufT);
    aggregate_kernel<<<(NTOT * C) / 256, 256, 0, stream>>>(bufT, idx, bufH);

    pool_head_kernel<<<NB, 256, 0, stream>>>(bufH, Wr, br, out);
}

// Round 2
// 277.132 us; speedup vs baseline: 1.2165x; 1.2165x over previous
//
#include <hip/hip_runtime.h>
#include <cstddef>

#define NB 256     // graphs
#define M 512      // nodes per graph
#define KNN 6      // neighbors
#define C 32       // channels
#define NTOT (NB*M)

// ---------------------------------------------------------------------------
// KNN v2: 4 blocks per graph, each block = 512 threads = 4 column-parts x 128
// rows. Each thread scans 128 neighbors (branchless top-6 insert), candidates
// merged tie-stably in LDS. Distance math is bit-identical to the validated
// round-1 kernel (same fma chains), so the selected neighbor set is unchanged.
// 1024 blocks -> 4 blocks/CU -> 100% wave occupancy (needs VGPR <= 64).
// ---------------------------------------------------------------------------
__global__ __launch_bounds__(512) void knn_kernel(const float* __restrict__ pos,
                                                  int* __restrict__ idx)
{
    __shared__ float4 sp[M];          // x,y,z,sq  (broadcast reads)
    __shared__ float  cd[512][7];     // candidate dists, stride 7 (conflict-free)
    __shared__ int    ci[512][7];

    const int b      = blockIdx.x;
    const int g      = b >> 2;
    const int rchunk = b & 3;
    const int tid    = threadIdx.x;

    const float* p = pos + (size_t)g * M * 3;
    for (int i = tid; i < M; i += 512) {
        float x = p[3 * i], y = p[3 * i + 1], z = p[3 * i + 2];
        sp[i] = make_float4(x, y, z, fmaf(x, x, fmaf(y, y, z * z)));
    }
    __syncthreads();

    const int part = tid >> 7;        // 0..3  (wave-uniform -> LDS broadcast)
    const int rloc = tid & 127;       // 0..127
    const int row  = rchunk * 128 + rloc;

    const float4 pm = sp[row];
    const float xm = pm.x, ym = pm.y, zm = pm.z, sqm = pm.w;

    float d[KNN]; int id[KNN];
#pragma unroll
    for (int k = 0; k < KNN; k++) { d[k] = INFINITY; id[k] = -1; }

    const int n0 = part * 128;
#pragma unroll 4
    for (int jj = 0; jj < 128; jj++) {
        const int n = n0 + jj;
        const float4 pn = sp[n];
        float dot  = fmaf(xm, pn.x, fmaf(ym, pn.y, zm * pn.z));
        float dist = fmaf(-2.f, dot, sqm + pn.w);   // identical to round-1 formula
        // branchless sorted insert; strict < keeps earlier (lower) index on ties
#pragma unroll
        for (int k = KNN - 1; k > 0; k--) {
            bool ck  = dist < d[k];
            bool ck1 = dist < d[k - 1];
            d[k]  = ck1 ? d[k - 1]  : (ck ? dist : d[k]);
            id[k] = ck1 ? id[k - 1] : (ck ? n    : id[k]);
        }
        bool c0 = dist < d[0];
        d[0]  = c0 ? dist : d[0];
        id[0] = c0 ? n    : id[0];
    }

#pragma unroll
    for (int k = 0; k < KNN; k++) { cd[tid][k] = d[k]; ci[tid][k] = id[k]; }
    __syncthreads();

    if (tid < 128) {
        // merge 4 sorted 6-lists (parts scanned in ascending-n order ->
        // strict-< insertion is tie-stable toward lower index)
        float md[KNN]; int mi[KNN];
#pragma unroll
        for (int k = 0; k < KNN; k++) { md[k] = cd[tid][k]; mi[k] = ci[tid][k]; }
#pragma unroll
        for (int pp = 1; pp < 4; pp++) {
#pragma unroll
            for (int k = 0; k < KNN; k++) {
                float dist = cd[pp * 128 + tid][k];
                int   n    = ci[pp * 128 + tid][k];
#pragma unroll
                for (int q = KNN - 1; q > 0; q--) {
                    bool cq  = dist < md[q];
                    bool cq1 = dist < md[q - 1];
                    md[q] = cq1 ? md[q - 1] : (cq ? dist : md[q]);
                    mi[q] = cq1 ? mi[q - 1] : (cq ? n    : mi[q]);
                }
                bool c0 = dist < md[0];
                md[0] = c0 ? dist : md[0];
                mi[0] = c0 ? n    : mi[0];
            }
        }
        const int rowg = rchunk * 128 + tid;
        int* o = idx + ((size_t)g * M + rowg) * KNN;
#pragma unroll
        for (int k = 0; k < KNN; k++) o[k] = mi[k];
    }
}

// ---------------------------------------------------------------------------
// Fused 3-layer GCN + pool + head: one block per graph, one thread per node.
// h lives in registers; only T round-trips through a 64 KiB XOR-swizzled LDS
// buffer (elem (n,c) at n*32 + (c ^ (n&31)) -> gather spreads across banks).
// ---------------------------------------------------------------------------
template <int IN>
__device__ __forceinline__ void gcn_layer(float (&h)[C],
    const float* __restrict__ W1, const float* __restrict__ b1,
    const float* __restrict__ W2, const float* __restrict__ b2,
    float* Ts, int tid, const int (&j)[KNN])
{
    float m1[C];
#pragma unroll
    for (int o = 0; o < C; o++) {
        float a = b1[o];
#pragma unroll
        for (int i = 0; i < IN; i++) a = fmaf(W1[o * IN + i], h[i], a);
        m1[o] = fmaxf(a, 0.f);
    }
    const int sw = tid & 31;
#pragma unroll
    for (int o = 0; o < C; o++) {
        float a = b2[o];
#pragma unroll
        for (int i = 0; i < C; i++) a = fmaf(W2[o * C + i], m1[i], a);
        Ts[tid * C + (o ^ sw)] = a;
    }
    __syncthreads();

#pragma unroll
    for (int c = 0; c < C; c++) h[c] = -INFINITY;
#pragma unroll
    for (int k = 0; k < KNN; k++) {
        const int base = j[k] * C, s = j[k] & 31;
#pragma unroll
        for (int c = 0; c < C; c++)
            h[c] = fmaxf(h[c], Ts[base + (c ^ s)]);
    }
#pragma unroll
    for (int c = 0; c < C; c++) h[c] = fmaxf(h[c], 0.f);   // relu after max-agg
    __syncthreads();   // Ts reusable by next layer
}

__global__ __launch_bounds__(512) void fused_kernel(
    const float* __restrict__ x, const float* __restrict__ pos,
    const int* __restrict__ idx,
    const float* __restrict__ W1a, const float* __restrict__ b1a,
    const float* __restrict__ W2a, const float* __restrict__ b2a,
    const float* __restrict__ W1b, const float* __restrict__ b1b,
    const float* __restrict__ W2b, const float* __restrict__ b2b,
    const float* __restrict__ W1c, const float* __restrict__ b1c,
    const float* __restrict__ W2c, const float* __restrict__ b2c,
    const float* __restrict__ Wr,  const float* __restrict__ br,
    float* __restrict__ out)
{
    __shared__ float Ts[M * C];   // 64 KiB, XOR-swizzled
    const int g = blockIdx.x, tid = threadIdx.x;
    const int n = g * M + tid;

    float h[C];
    h[0] = x[n];
    h[1] = pos[3 * n];
    h[2] = pos[3 * n + 1];
    h[3] = pos[3 * n + 2];

    int j[KNN];
#pragma unroll
    for (int k = 0; k < KNN; k++) j[k] = idx[(size_t)n * KNN + k];

    gcn_layer<4>(h, W1a, b1a, W2a, b2a, Ts, tid, j);
    gcn_layer<C>(h, W1b, b1b, W2b, b2b, Ts, tid, j);
    gcn_layer<C>(h, W1c, b1c, W2c, b2c, Ts, tid, j);

    // ---- global max pool over 512 nodes (reuse Ts) ----
    const int sw = tid & 31;
#pragma unroll
    for (int c = 0; c < C; c++) Ts[tid * C + (c ^ sw)] = h[c];
    __syncthreads();

    const int c = tid & 31, grp = tid >> 5;   // 16 groups x 32 nodes
    float mx = -INFINITY;
#pragma unroll
    for (int i = 0; i < 32; i++) {
        const int nn = grp * 32 + i;
        mx = fmaxf(mx, Ts[nn * C + (c ^ (nn & 31))]);
    }
    __syncthreads();           // all reads of swizzled H done
    Ts[grp * C + c] = mx;      // red[16][32]
    __syncthreads();

    if (tid < C) {
        float m2 = Ts[tid];
#pragma unroll
        for (int r = 1; r < 16; r++) m2 = fmaxf(m2, Ts[r * C + tid]);
        Ts[512 + tid] = m2;    // gmax[32]
    }
    __syncthreads();

    if (tid < 6) {
        float a = br[tid];
#pragma unroll
        for (int i = 0; i < C; i++) a = fmaf(Wr[tid * C + i], Ts[512 + i], a);
        out[g * 6 + tid] = a;
    }
}

extern "C" void kernel_launch(void* const* d_in, const int* in_sizes, int n_in,
                              void* d_out, int out_size, void* d_ws, size_t ws_size,
                              hipStream_t stream) {
    const float* x   = (const float*)d_in[0];
    const float* pos = (const float*)d_in[1];
    // d_in[2] = batch (int64) unused: nodes are contiguous M-per-graph
    const float* W1a = (const float*)d_in[3];
    const float* b1a = (const float*)d_in[4];
    const float* W2a = (const float*)d_in[5];
    const float* b2a = (const float*)d_in[6];
    const float* W1b = (const float*)d_in[7];
    const float* b1b = (const float*)d_in[8];
    const float* W2b = (const float*)d_in[9];
    const float* b2b = (const float*)d_in[10];
    const float* W1c = (const float*)d_in[11];
    const float* b1c = (const float*)d_in[12];
    const float* W2c = (const float*)d_in[13];
    const float* b2c = (const float*)d_in[14];
    const float* Wr  = (const float*)d_in[15];
    const float* br  = (const float*)d_in[16];

    int*   idx = (int*)d_ws;   // NTOT*6 ints = 3 MB
    float* out = (float*)d_out;

    knn_kernel<<<NB * 4, 512, 0, stream>>>(pos, idx);

    fused_kernel<<<NB, 512, 0, stream>>>(x, pos, idx,
                                         W1a, b1a, W2a, b2a,
                                         W1b, b1b, W2b, b2b,
                                         W1c, b1c, W2c, b2c,
                                         Wr, br, out);
}

// Round 3
// 244.599 us; speedup vs baseline: 1.3783x; 1.1330x over previous
//
#include <hip/hip_runtime.h>
#include <cstddef>

#define NB 256     // graphs
#define M 512      // nodes per graph
#define KNN 6      // neighbors
#define C 32       // channels
#define NTOT (NB*M)

// ---------------------------------------------------------------------------
// KNN: 4 blocks per graph, 512 threads = 4 column-parts x 128 rows.
// Math bit-identical to the validated round-2 kernel (absmax 0.0); only the
// output layout changed: idx stored transposed [k][NTOT] with GLOBAL node ids
// so consumer loads are coalesced.
// ---------------------------------------------------------------------------
__global__ __launch_bounds__(512) void knn_kernel(const float* __restrict__ pos,
                                                  int* __restrict__ idx)
{
    __shared__ float4 sp[M];          // x,y,z,sq (wave-uniform broadcast reads)
    __shared__ float  cd[512][7];     // stride 7: conflict-free write/read
    __shared__ int    ci[512][7];

    const int b      = blockIdx.x;
    const int g      = b >> 2;
    const int rchunk = b & 3;
    const int tid    = threadIdx.x;

    const float* p = pos + (size_t)g * M * 3;
    for (int i = tid; i < M; i += 512) {
        float x = p[3 * i], y = p[3 * i + 1], z = p[3 * i + 2];
        sp[i] = make_float4(x, y, z, fmaf(x, x, fmaf(y, y, z * z)));
    }
    __syncthreads();

    const int part = tid >> 7;        // wave-uniform
    const int rloc = tid & 127;
    const int row  = rchunk * 128 + rloc;

    const float4 pm = sp[row];
    const float xm = pm.x, ym = pm.y, zm = pm.z, sqm = pm.w;

    float d[KNN]; int id[KNN];
#pragma unroll
    for (int k = 0; k < KNN; k++) { d[k] = INFINITY; id[k] = -1; }

    const int n0 = part * 128;
#pragma unroll 4
    for (int jj = 0; jj < 128; jj++) {
        const int n = n0 + jj;
        const float4 pn = sp[n];
        float dot  = fmaf(xm, pn.x, fmaf(ym, pn.y, zm * pn.z));
        float dist = fmaf(-2.f, dot, sqm + pn.w);   // identical rounding to ref path
        // branchless sorted insert; strict < keeps lower index on exact ties
#pragma unroll
        for (int k = KNN - 1; k > 0; k--) {
            bool ck  = dist < d[k];
            bool ck1 = dist < d[k - 1];
            d[k]  = ck1 ? d[k - 1]  : (ck ? dist : d[k]);
            id[k] = ck1 ? id[k - 1] : (ck ? n    : id[k]);
        }
        bool c0 = dist < d[0];
        d[0]  = c0 ? dist : d[0];
        id[0] = c0 ? n    : id[0];
    }

#pragma unroll
    for (int k = 0; k < KNN; k++) { cd[tid][k] = d[k]; ci[tid][k] = id[k]; }
    __syncthreads();

    if (tid < 128) {
        float md[KNN]; int mi[KNN];
#pragma unroll
        for (int k = 0; k < KNN; k++) { md[k] = cd[tid][k]; mi[k] = ci[tid][k]; }
#pragma unroll
        for (int pp = 1; pp < 4; pp++) {
#pragma unroll
            for (int k = 0; k < KNN; k++) {
                float dist = cd[pp * 128 + tid][k];
                int   n    = ci[pp * 128 + tid][k];
#pragma unroll
                for (int q = KNN - 1; q > 0; q--) {
                    bool cq  = dist < md[q];
                    bool cq1 = dist < md[q - 1];
                    md[q] = cq1 ? md[q - 1] : (cq ? dist : md[q]);
                    mi[q] = cq1 ? mi[q - 1] : (cq ? n    : mi[q]);
                }
                bool c0 = dist < md[0];
                md[0] = c0 ? dist : md[0];
                mi[0] = c0 ? n    : mi[0];
            }
        }
        const int node = g * M + rchunk * 128 + tid;   // global node id
#pragma unroll
        for (int k = 0; k < KNN; k++)
            idx[k * NTOT + node] = g * M + mi[k];      // transposed, global ids
    }
}

// ---------------------------------------------------------------------------
// Layer 1: T0[n] = MLP_a([x, pos]) — no gather (messages depend on source only)
// ---------------------------------------------------------------------------
__global__ __launch_bounds__(256) void layer1_kernel(
    const float* __restrict__ x, const float* __restrict__ pos,
    const float* __restrict__ W1, const float* __restrict__ b1,
    const float* __restrict__ W2, const float* __restrict__ b2,
    float* __restrict__ Tout)
{
    const int n = blockIdx.x * 256 + threadIdx.x;
    float h0 = x[n], h1 = pos[3 * n], h2 = pos[3 * n + 1], h3 = pos[3 * n + 2];

    float m1[C];
#pragma unroll
    for (int o = 0; o < C; o++) {
        float a = b1[o];
        a = fmaf(W1[o * 4 + 0], h0, a);
        a = fmaf(W1[o * 4 + 1], h1, a);
        a = fmaf(W1[o * 4 + 2], h2, a);
        a = fmaf(W1[o * 4 + 3], h3, a);
        m1[o] = fmaxf(a, 0.f);
    }

    float4* orow = (float4*)(Tout + (size_t)n * C);
#pragma unroll
    for (int o4 = 0; o4 < 8; o4++) {
        float4 v;
        float* vp = &v.x;
#pragma unroll
        for (int u = 0; u < 4; u++) {
            const int o = o4 * 4 + u;
            float a = b2[o];
#pragma unroll
            for (int i = 0; i < C; i++) a = fmaf(W2[o * C + i], m1[i], a);
            vp[u] = a;
        }
        orow[o4] = v;
    }
}

// ---------------------------------------------------------------------------
// Layers 2,3: h = relu(max_k Tin[nbr]); Tout = MLP(h). Full occupancy,
// float4 row gathers (L1 coalesces the 8 loads per 128-B row).
// ---------------------------------------------------------------------------
__global__ __launch_bounds__(256, 4) void layer_kernel(
    const float* __restrict__ Tin, const int* __restrict__ idx,
    const float* __restrict__ W1, const float* __restrict__ b1,
    const float* __restrict__ W2, const float* __restrict__ b2,
    float* __restrict__ Tout)
{
    const int n = blockIdx.x * 256 + threadIdx.x;

    float h[C];
#pragma unroll
    for (int c = 0; c < C; c++) h[c] = -INFINITY;
#pragma unroll
    for (int k = 0; k < KNN; k++) {
        const int j = idx[k * NTOT + n];               // coalesced
        const float4* r = (const float4*)(Tin + (size_t)j * C);
#pragma unroll
        for (int q = 0; q < 8; q++) {
            float4 v = r[q];
            h[4 * q + 0] = fmaxf(h[4 * q + 0], v.x);
            h[4 * q + 1] = fmaxf(h[4 * q + 1], v.y);
            h[4 * q + 2] = fmaxf(h[4 * q + 2], v.z);
            h[4 * q + 3] = fmaxf(h[4 * q + 3], v.w);
        }
    }
#pragma unroll
    for (int c = 0; c < C; c++) h[c] = fmaxf(h[c], 0.f);

    float m1[C];
#pragma unroll
    for (int o = 0; o < C; o++) {
        float a = b1[o];
#pragma unroll
        for (int i = 0; i < C; i++) a = fmaf(W1[o * C + i], h[i], a);
        m1[o] = fmaxf(a, 0.f);
    }

    float4* orow = (float4*)(Tout + (size_t)n * C);
#pragma unroll
    for (int o4 = 0; o4 < 8; o4++) {
        float4 v;
        float* vp = &v.x;
#pragma unroll
        for (int u = 0; u < 4; u++) {
            const int o = o4 * 4 + u;
            float a = b2[o];
#pragma unroll
            for (int i = 0; i < C; i++) a = fmaf(W2[o * C + i], m1[i], a);
            vp[u] = a;
        }
        orow[o4] = v;
    }
}

// ---------------------------------------------------------------------------
// Pool+head: h3 = relu(max_k T2[nbr]); per-graph max over nodes; 6-dim head.
// One block per graph, 512 threads. XOR-swizzled LDS reduction.
// ---------------------------------------------------------------------------
__global__ __launch_bounds__(512) void pool_head_kernel(
    const float* __restrict__ Tin, const int* __restrict__ idx,
    const float* __restrict__ Wr, const float* __restrict__ br,
    float* __restrict__ out)
{
    __shared__ float S[M * C];   // 64 KiB, elem (r,c) at r*32 + (c ^ (r&31))
    const int g = blockIdx.x, t = threadIdx.x;
    const int n = g * M + t;

    float h[C];
#pragma unroll
    for (int c = 0; c < C; c++) h[c] = -INFINITY;
#pragma unroll
    for (int k = 0; k < KNN; k++) {
        const int j = idx[k * NTOT + n];
        const float4* r = (const float4*)(Tin + (size_t)j * C);
#pragma unroll
        for (int q = 0; q < 8; q++) {
            float4 v = r[q];
            h[4 * q + 0] = fmaxf(h[4 * q + 0], v.x);
            h[4 * q + 1] = fmaxf(h[4 * q + 1], v.y);
            h[4 * q + 2] = fmaxf(h[4 * q + 2], v.z);
            h[4 * q + 3] = fmaxf(h[4 * q + 3], v.w);
        }
    }

    const int sw = t & 31;
#pragma unroll
    for (int c = 0; c < C; c++) S[t * C + (c ^ sw)] = fmaxf(h[c], 0.f);
    __syncthreads();

    // tree max-reduce over rows: 512 -> 32 (s multiple of 32 => same swizzle)
    for (int s = 256; s >= 32; s >>= 1) {
        if (t < s) {
#pragma unroll
            for (int c = 0; c < C; c++) {
                float a = S[t * C + (c ^ sw)];
                float b = S[(t + s) * C + (c ^ sw)];
                S[t * C + (c ^ sw)] = fmaxf(a, b);
            }
        }
        __syncthreads();
    }

    if (t < C) {   // wave 0: rows 0..31 -> gmax, bank-conflict-free (c^r)
        float m = -INFINITY;
#pragma unroll
        for (int r = 0; r < 32; r++) m = fmaxf(m, S[r * C + (t ^ r)]);
        S[t] = m;  // lane t owns addr t (row 0): no cross-lane hazard
    }
    if (t < 6) {
        float a = br[t];
#pragma unroll
        for (int i = 0; i < C; i++) a = fmaf(Wr[t * C + i], S[i], a);
        out[g * 6 + t] = a;
    }
}

extern "C" void kernel_launch(void* const* d_in, const int* in_sizes, int n_in,
                              void* d_out, int out_size, void* d_ws, size_t ws_size,
                              hipStream_t stream) {
    const float* x   = (const float*)d_in[0];
    const float* pos = (const float*)d_in[1];
    // d_in[2] = batch (int64) unused: nodes are contiguous M-per-graph
    const float* W1a = (const float*)d_in[3];
    const float* b1a = (const float*)d_in[4];
    const float* W2a = (const float*)d_in[5];
    const float* b2a = (const float*)d_in[6];
    const float* W1b = (const float*)d_in[7];
    const float* b1b = (const float*)d_in[8];
    const float* W2b = (const float*)d_in[9];
    const float* b2b = (const float*)d_in[10];
    const float* W1c = (const float*)d_in[11];
    const float* b1c = (const float*)d_in[12];
    const float* W2c = (const float*)d_in[13];
    const float* b2c = (const float*)d_in[14];
    const float* Wr  = (const float*)d_in[15];
    const float* br  = (const float*)d_in[16];

    char* ws = (char*)d_ws;
    int*   idx = (int*)ws;                                  // 3 MB  [KNN][NTOT]
    float* Ta  = (float*)(ws + (size_t)4  * 1024 * 1024);   // 16.8 MB
    float* Tb  = (float*)(ws + (size_t)24 * 1024 * 1024);   // 16.8 MB
    float* out = (float*)d_out;

    knn_kernel<<<NB * 4, 512, 0, stream>>>(pos, idx);

    layer1_kernel<<<NTOT / 256, 256, 0, stream>>>(x, pos, W1a, b1a, W2a, b2a, Ta);
    layer_kernel <<<NTOT / 256, 256, 0, stream>>>(Ta, idx, W1b, b1b, W2b, b2b, Tb);
    layer_kernel <<<NTOT / 256, 256, 0, stream>>>(Tb, idx, W1c, b1c, W2c, b2c, Ta);
    pool_head_kernel<<<NB, 512, 0, stream>>>(Ta, idx, Wr, br, out);
}